// Round 1
// baseline (88.936 us; speedup 1.0000x reference)
//
#include <hip/hip_runtime.h>

#define HOP      512
#define WIN      1024
#define NHARM    100
#define TFRAMES  400
#define INV_SR   (1.0f / 44100.0f)
#define INV_2PI  0.15915494309189535f

// cos(2*pi*t), t in revolutions. v_cos_f32 takes revolutions; fract for range
// reduction per ISA guidance.
__device__ __forceinline__ float cos_rev(float t) {
#if defined(__has_builtin)
#if __has_builtin(__builtin_amdgcn_cosf) && __has_builtin(__builtin_amdgcn_fractf)
    return __builtin_amdgcn_cosf(__builtin_amdgcn_fractf(t));
#else
    return __cosf(t * 6.283185307179586f);
#endif
#else
    return __cosf(t * 6.283185307179586f);
#endif
}

// One block per (b, q) output chunk of HOP samples.
// out[b, q*HOP + r] = hann[HOP+r] * frame_q(r) + hann[r] * frame_{q+1}(r - HOP)
// hann[HOP+r] = 0.5 + 0.5*cos(2*pi*r/WIN), hann[r] = 0.5 - 0.5*cos(2*pi*r/WIN)
__global__ __launch_bounds__(128) void sinstack_kernel(
    const float* __restrict__ ampl,
    const float* __restrict__ phase,
    const float* __restrict__ f0,
    float* __restrict__ out)
{
    const int q   = blockIdx.x;   // output chunk / frame index, 0..TFRAMES-1
    const int b   = blockIdx.y;   // batch
    const int tid = threadIdx.x;  // 0..127

    __shared__ float sA[2 * NHARM];
    __shared__ float sF[2 * NHARM];
    __shared__ float sP[2 * NHARM];

    // Stage harmonic params for frame q (group 0) and frame q+1 (group 1).
    for (int i = tid; i < 2 * NHARM; i += 128) {
        const int grp = (i >= NHARM) ? 1 : 0;
        const int n   = i - grp * NHARM;
        const int t   = q + grp;
        float a = 0.0f, fr = 0.0f, ph = 0.0f;
        if (t < TFRAMES) {
            const int idx = (b * NHARM + n) * TFRAMES + t;
            a  = ampl[idx];
            fr = f0[idx] * INV_SR;        // revolutions per sample
            ph = phase[idx] * INV_2PI;    // revolutions
            if (grp) ph -= (float)HOP * fr;  // fold x = r - HOP into phase
        }
        sA[i] = a; sF[i] = fr; sP[i] = ph;
    }
    __syncthreads();

    const float r0 = (float)(tid * 4);

    float acc1[4] = {0.f, 0.f, 0.f, 0.f};  // frame q   contribution
    float acc2[4] = {0.f, 0.f, 0.f, 0.f};  // frame q+1 contribution

    for (int n = 0; n < NHARM; ++n) {
        const float a = sA[n], fr = sF[n], ph = sP[n];
#pragma unroll
        for (int j = 0; j < 4; ++j)
            acc1[j] += a * cos_rev(fmaf(fr, r0 + (float)j, ph));
    }
    for (int n = NHARM; n < 2 * NHARM; ++n) {
        const float a = sA[n], fr = sF[n], ph = sP[n];
#pragma unroll
        for (int j = 0; j < 4; ++j)
            acc2[j] += a * cos_rev(fmaf(fr, r0 + (float)j, ph));
    }

    float4 o;
    float* op = &o.x;
#pragma unroll
    for (int j = 0; j < 4; ++j) {
        // c = cos(2*pi*(r)/WIN); arg in [0,0.5), no fract needed
        const float c = cos_rev((r0 + (float)j) * (1.0f / (float)WIN));
        op[j] = 0.5f * ((acc1[j] + acc2[j]) + c * (acc1[j] - acc2[j]));
    }

    float4* outp = (float4*)(out + ((size_t)b * TFRAMES + q) * HOP + tid * 4);
    *outp = o;
}

extern "C" void kernel_launch(void* const* d_in, const int* in_sizes, int n_in,
                              void* d_out, int out_size, void* d_ws, size_t ws_size,
                              hipStream_t stream) {
    const float* ampl  = (const float*)d_in[0];
    const float* phase = (const float*)d_in[1];
    const float* f0    = (const float*)d_in[2];
    float* out = (float*)d_out;

    const int B = in_sizes[0] / (NHARM * TFRAMES);  // = 4
    dim3 grid(TFRAMES, B);
    sinstack_kernel<<<grid, 128, 0, stream>>>(ampl, phase, f0, out);
}

// Round 2
// 77.168 us; speedup vs baseline: 1.1525x; 1.1525x over previous
//
#include <hip/hip_runtime.h>

#define HOP      512
#define WIN      1024
#define NHARM    100
#define TFRAMES  400
#define INV_SR   (1.0f / 44100.0f)
#define INV_2PI  0.15915494309189535f

// cos(2*pi*t), t in revolutions. v_cos_f32 takes revolutions; v_fract for
// range reduction.
__device__ __forceinline__ float cos_rev(float t) {
    return __builtin_amdgcn_cosf(__builtin_amdgcn_fractf(t));
}

// One block (64 threads) per (b, q) output chunk of HOP samples; 8 samples
// per thread. Chebyshev recurrence: cos(th + (j+1)dr) = tcf*cos(th + j*dr)
// - cos(th + (j-1)dr), tcf = 2*cos(dr) precomputed per harmonic at staging.
__global__ __launch_bounds__(64) void sinstack_kernel(
    const float* __restrict__ ampl,
    const float* __restrict__ phase,
    const float* __restrict__ f0,
    float* __restrict__ out)
{
    const int q   = blockIdx.x;   // frame/chunk index 0..TFRAMES-1
    const int b   = blockIdx.y;   // batch
    const int tid = threadIdx.x;  // 0..63

    // {ampl, fr (rev/sample), phase (rev, group-1 pre-shifted), 2*cos(2pi*fr)}
    __shared__ float4 sPar[2 * NHARM];

    for (int i = tid; i < 2 * NHARM; i += 64) {
        const int grp = (i >= NHARM) ? 1 : 0;
        const int n   = i - grp * NHARM;
        const int t   = q + grp;
        float4 p = make_float4(0.f, 0.f, 0.f, 2.f);
        if (t < TFRAMES) {
            const int idx = (b * NHARM + n) * TFRAMES + t;
            const float a  = ampl[idx];
            const float fr = f0[idx] * INV_SR;       // revolutions/sample
            float ph = phase[idx] * INV_2PI;
            if (grp) ph -= (float)HOP * fr;          // fold x = r - HOP
            p = make_float4(a, fr, ph, 2.0f * cos_rev(fr));
        }
        sPar[i] = p;
    }
    __syncthreads();

    const float r0 = (float)(tid * 8);

    float acc1[8] = {0,0,0,0,0,0,0,0};
    float acc2[8] = {0,0,0,0,0,0,0,0};

#pragma unroll 4
    for (int n = 0; n < NHARM; ++n) {
        const float4 p = sPar[n];
        const float t0 = fmaf(p.y, r0, p.z);
        float prev = cos_rev(t0);
        float cur  = cos_rev(t0 + p.y);
        acc1[0] = fmaf(p.x, prev, acc1[0]);
        acc1[1] = fmaf(p.x, cur,  acc1[1]);
#pragma unroll
        for (int j = 2; j < 8; ++j) {
            const float nxt = fmaf(p.w, cur, -prev);
            acc1[j] = fmaf(p.x, nxt, acc1[j]);
            prev = cur; cur = nxt;
        }
    }
#pragma unroll 4
    for (int n = NHARM; n < 2 * NHARM; ++n) {
        const float4 p = sPar[n];
        const float t0 = fmaf(p.y, r0, p.z);
        float prev = cos_rev(t0);
        float cur  = cos_rev(t0 + p.y);
        acc2[0] = fmaf(p.x, prev, acc2[0]);
        acc2[1] = fmaf(p.x, cur,  acc2[1]);
#pragma unroll
        for (int j = 2; j < 8; ++j) {
            const float nxt = fmaf(p.w, cur, -prev);
            acc2[j] = fmaf(p.x, nxt, acc2[j]);
            prev = cur; cur = nxt;
        }
    }

    // out = w1*S1 + w2*S2, w1 = 0.5 + 0.5*c, w2 = 0.5 - 0.5*c, c = cos(2pi*r/WIN)
    float o[8];
#pragma unroll
    for (int j = 0; j < 8; ++j) {
        const float c = cos_rev((r0 + (float)j) * (1.0f / (float)WIN));
        o[j] = 0.5f * ((acc1[j] + acc2[j]) + c * (acc1[j] - acc2[j]));
    }

    float* outp = out + ((size_t)b * TFRAMES + q) * HOP + tid * 8;
    *(float4*)(outp)     = make_float4(o[0], o[1], o[2], o[3]);
    *(float4*)(outp + 4) = make_float4(o[4], o[5], o[6], o[7]);
}

extern "C" void kernel_launch(void* const* d_in, const int* in_sizes, int n_in,
                              void* d_out, int out_size, void* d_ws, size_t ws_size,
                              hipStream_t stream) {
    const float* ampl  = (const float*)d_in[0];
    const float* phase = (const float*)d_in[1];
    const float* f0    = (const float*)d_in[2];
    float* out = (float*)d_out;

    const int B = in_sizes[0] / (NHARM * TFRAMES);  // = 4
    dim3 grid(TFRAMES, B);
    sinstack_kernel<<<grid, 64, 0, stream>>>(ampl, phase, f0, out);
}